// Round 6
// baseline (1224.553 us; speedup 1.0000x reference)
//
#include <hip/hip_runtime.h>
#include <cmath>

#define NLEV 16
#define TPB 256

typedef float v4f __attribute__((ext_vector_type(4)));
typedef float v2f __attribute__((ext_vector_type(2)));

// Level metadata replicated from the reference's _level_meta() (float64 host
// math; boundary levels 5/10/15 land 1e-5 ABOVE the integer -> res=65/257/1025).
static constexpr unsigned kRes[NLEV] = {16u,22u,28u,37u,49u,65u,85u,112u,148u,195u,257u,338u,446u,589u,777u,1025u};
static constexpr unsigned kMsz[NLEV] = {4096u,10648u,21952u,50656u,117656u,274632u,
  524288u,524288u,524288u,524288u,524288u,524288u,524288u,524288u,524288u,524288u};
static constexpr unsigned kOff[NLEV] = {0u,4096u,14744u,36696u,87352u,205008u,479640u,1003928u,
  1528216u,2052504u,2576792u,3101080u,3625368u,4149656u,4673944u,5198232u};
static constexpr int kDense[NLEV] = {1,1,1,1,1,1,0,0,0,0,0,0,0,0,0,0};

struct ScaleParams { float s[NLEV]; };

// 16-B load that is only guaranteed 8-B aligned (dense corner-pair load).
__device__ __forceinline__ v4f load4_a8(const float* p) {
  const float* q = (const float*)__builtin_assume_aligned((const void*)p, 8);
  v4f v;
  __builtin_memcpy(&v, q, 16);
  return v;
}

// Stage 512 points (2 per thread) of positions through LDS.
// stride 6 floats: gcd(6,32)=2 -> 2-way LDS aliasing, free on CDNA4.
__device__ __forceinline__ void load_pos2(const float* __restrict__ pos, float* sp,
                                          int tid, size_t pbase,
                                          float& px0, float& py0, float& pz0,
                                          float& px1, float& py1, float& pz1) {
  const float* src = pos + pbase * 3;
#pragma unroll
  for (int k = 0; k < 6; ++k)
    sp[tid + k * TPB] = __builtin_nontemporal_load(src + tid + k * TPB);
  __syncthreads();
  px0 = sp[tid * 6 + 0]; py0 = sp[tid * 6 + 1]; pz0 = sp[tid * 6 + 2];
  px1 = sp[tid * 6 + 3]; py1 = sp[tid * 6 + 4]; pz1 = sp[tid * 6 + 5];
}

// ---------------------------------------------------------------------------
// DENSE (round-1 form, fastest measured dense variant ~200us):
// 2 pts/thread, paired-corner 16B gathers (x and x+1 corners are adjacent
// table entries), branchless wrap patch from a hoisted scalar load of entry 0.
// No sched_barrier: the compiler software-pipelines across the level loop.
// Accumulation order matches the reference 8-corner loop exactly.
// ---------------------------------------------------------------------------

__device__ __forceinline__ v2f dense_point(const float2* __restrict__ tab2,
                                           float px, float py, float pz,
                                           float scale, unsigned r, unsigned msz,
                                           unsigned off) {
  const float x = px * scale + 0.5f;
  const float y = py * scale + 0.5f;
  const float z = pz * scale + 0.5f;
  const float xf = floorf(x), yf = floorf(y), zf = floorf(z);
  const float tx = x - xf, ty = y - yf, tz = z - zf;
  const unsigned xi = (unsigned)xf, yi = (unsigned)yf, zi = (unsigned)zf;

  const unsigned hy[2] = {yi * r, (yi + 1u) * r};
  const unsigned hz[2] = {zi * r * r, (zi + 1u) * r * r};
  const float wx0 = 1.0f - tx, wx1 = tx;
  const float wy[2] = {1.0f - ty, ty};
  const float wz[2] = {1.0f - tz, tz};

  // wrap-patch value: corner x+1 of cell with idx==msz-1 lives at entry 0.
  const float2 g = tab2[off];

  float a0 = 0.0f, a1 = 0.0f;
#pragma unroll
  for (int c = 0; c < 4; ++c) {
    const unsigned h = xi + hy[c & 1] + hz[c >> 1];
    const unsigned idx = (h >= msz) ? (h - msz) : h;
    v4f f = load4_a8((const float*)(tab2 + (off + idx)));
    const bool wrap = (idx == msz - 1u);
    f.z = wrap ? g.x : f.z;
    f.w = wrap ? g.y : f.w;
    const float wyv = wy[c & 1], wzv = wz[c >> 1];
    const float w0 = (wx0 * wyv) * wzv;
    const float w1 = (wx1 * wyv) * wzv;
    a0 = fmaf(w0, f.x, a0);
    a1 = fmaf(w0, f.y, a1);
    a0 = fmaf(w1, f.z, a0);
    a1 = fmaf(w1, f.w, a1);
  }
  v2f rr; rr.x = a0; rr.y = a1;
  return rr;
}

__global__ __launch_bounds__(TPB, 4) void dense_levels2(
    const float* __restrict__ pos, const float* __restrict__ table,
    float* __restrict__ ws, ScaleParams spar, int npts)
{
  __shared__ float sp[TPB * 6];
  const int tid = threadIdx.x;
  const size_t pbase = (size_t)blockIdx.x * (TPB * 2);
  float px0, py0, pz0, px1, py1, pz1;
  load_pos2(pos, sp, tid, pbase, px0, py0, pz0, px1, py1, pz1);

  const float2* __restrict__ tab2 = (const float2*)table;
#pragma unroll
  for (int L = 0; L < 6; ++L) {
    const v2f r0 = dense_point(tab2, px0, py0, pz0, spar.s[L], kRes[L], kMsz[L], kOff[L]);
    const v2f r1 = dense_point(tab2, px1, py1, pz1, spar.s[L], kRes[L], kMsz[L], kOff[L]);
    v4f v; v.x = r0.x; v.y = r0.y; v.z = r1.x; v.w = r1.y;
    __builtin_nontemporal_store(v, (v4f*)ws + ((size_t)L * npts + pbase) / 2 + tid);
  }
}

// ---------------------------------------------------------------------------
// HASH (round-6 experiment: XOR-hash x-pairing to cut unique cache lines).
// For corner pair (2p, 2p+1): j0=(xi^h)&M, j1=((xi+1)^h)&M. When xi is even,
// j1 == j0^1 -> both corners live in the same 16B-aligned entry pair (same
// 64B line). Branchless: always load the 16B chunk at j0&~1 AND the 8B entry
// at j1; select. Even xi (50%): both loads same line -> 4 unique lines/point.
// Odd xi: 8 (unchanged). E[lines] = 6 vs 8 (-25%). Values and FMA order are
// bit-identical to the reference. This discriminates line-wall vs request-
// wall: null here => request wall => declared roofline at ~490us hash.
// ---------------------------------------------------------------------------

__global__ __launch_bounds__(TPB, 4) void hash_fused(
    const float* __restrict__ pos, const float* __restrict__ table,
    float* __restrict__ ws, ScaleParams spar, int lvlShift, int npts)
{
  __shared__ float sp[TPB * 6];
  const int tid = threadIdx.x;
  const int lvl = 6 + (int)(blockIdx.x >> lvlShift);
  const unsigned pb = blockIdx.x & ((1u << lvlShift) - 1u);

  // uniform scalar select of this block's scale (avoids dynamic kernarg index)
  float scale = 0.0f;
#pragma unroll
  for (int l = 6; l < NLEV; ++l) if (l == lvl) scale = spar.s[l];
  const unsigned off = kOff[6] + (unsigned)(lvl - 6) * 524288u;

  const size_t pbase = (size_t)pb * (TPB * 2);
  float px0, py0, pz0, px1, py1, pz1;
  load_pos2(pos, sp, tid, pbase, px0, py0, pz0, px1, py1, pz1);

  unsigned i0[8], i1[8];
  float    w0[8], w1[8];
  bool even0, even1;
  {
    const float x = px0 * scale + 0.5f;
    const float y = py0 * scale + 0.5f;
    const float z = pz0 * scale + 0.5f;
    const float xf = floorf(x), yf = floorf(y), zf = floorf(z);
    const float tx = x - xf, ty = y - yf, tz = z - zf;
    const unsigned xi = (unsigned)xf, yi = (unsigned)yf, zi = (unsigned)zf;
    even0 = ((xi & 1u) == 0u);
    const unsigned hx[2] = {xi, xi + 1u};
    const unsigned hy[2] = {yi * 2654435761u, (yi + 1u) * 2654435761u};
    const unsigned hz[2] = {zi * 805459861u,  (zi + 1u) * 805459861u};
    const float wx[2] = {1.0f - tx, tx};
    const float wy[2] = {1.0f - ty, ty};
    const float wz[2] = {1.0f - tz, tz};
#pragma unroll
    for (int c = 0; c < 8; ++c) {
      i0[c] = (hx[c & 1] ^ hy[(c >> 1) & 1] ^ hz[(c >> 2) & 1]) & 524287u;
      w0[c] = wx[c & 1] * wy[(c >> 1) & 1] * wz[(c >> 2) & 1];
    }
  }
  {
    const float x = px1 * scale + 0.5f;
    const float y = py1 * scale + 0.5f;
    const float z = pz1 * scale + 0.5f;
    const float xf = floorf(x), yf = floorf(y), zf = floorf(z);
    const float tx = x - xf, ty = y - yf, tz = z - zf;
    const unsigned xi = (unsigned)xf, yi = (unsigned)yf, zi = (unsigned)zf;
    even1 = ((xi & 1u) == 0u);
    const unsigned hx[2] = {xi, xi + 1u};
    const unsigned hy[2] = {yi * 2654435761u, (yi + 1u) * 2654435761u};
    const unsigned hz[2] = {zi * 805459861u,  (zi + 1u) * 805459861u};
    const float wx[2] = {1.0f - tx, tx};
    const float wy[2] = {1.0f - ty, ty};
    const float wz[2] = {1.0f - tz, tz};
#pragma unroll
    for (int c = 0; c < 8; ++c) {
      i1[c] = (hx[c & 1] ^ hy[(c >> 1) & 1] ^ hz[(c >> 2) & 1]) & 524287u;
      w1[c] = wx[c & 1] * wy[(c >> 1) & 1] * wz[(c >> 2) & 1];
    }
  }

  // Batch-issue: per corner-pair, one 16B chunk (covers j0 and j0^1) plus the
  // 8B entry at j1 (redundant same-line when xi even; needed when odd).
  const v2f* __restrict__ t2 = (const v2f*)table + off;
  v4f c0[4], c1[4];
  v2f x0[4], x1[4];
#pragma unroll
  for (int p = 0; p < 4; ++p) c0[p] = *(const v4f*)(t2 + (i0[2*p] & ~1u));
#pragma unroll
  for (int p = 0; p < 4; ++p) x0[p] = t2[i0[2*p + 1]];
#pragma unroll
  for (int p = 0; p < 4; ++p) c1[p] = *(const v4f*)(t2 + (i1[2*p] & ~1u));
#pragma unroll
  for (int p = 0; p < 4; ++p) x1[p] = t2[i1[2*p + 1]];
  __builtin_amdgcn_sched_barrier(0);     // keep the gather group issued before use

  float a0 = 0.0f, a1 = 0.0f, b0 = 0.0f, b1 = 0.0f;
#pragma unroll
  for (int p = 0; p < 4; ++p) {
    const bool hi = (i0[2*p] & 1u) != 0u;          // j0's half of the chunk
    const float e0x = hi ? c0[p].z : c0[p].x;
    const float e0y = hi ? c0[p].w : c0[p].y;
    const float exE = hi ? c0[p].x : c0[p].z;       // j0^1 half (even-xi case)
    const float eyE = hi ? c0[p].y : c0[p].w;
    const float e1x = even0 ? exE : x0[p].x;
    const float e1y = even0 ? eyE : x0[p].y;
    a0 = fmaf(w0[2*p],     e0x, a0);
    a1 = fmaf(w0[2*p],     e0y, a1);
    a0 = fmaf(w0[2*p + 1], e1x, a0);
    a1 = fmaf(w0[2*p + 1], e1y, a1);
  }
#pragma unroll
  for (int p = 0; p < 4; ++p) {
    const bool hi = (i1[2*p] & 1u) != 0u;
    const float e0x = hi ? c1[p].z : c1[p].x;
    const float e0y = hi ? c1[p].w : c1[p].y;
    const float exE = hi ? c1[p].x : c1[p].z;
    const float eyE = hi ? c1[p].y : c1[p].w;
    const float e1x = even1 ? exE : x1[p].x;
    const float e1y = even1 ? eyE : x1[p].y;
    b0 = fmaf(w1[2*p],     e0x, b0);
    b1 = fmaf(w1[2*p],     e0y, b1);
    b0 = fmaf(w1[2*p + 1], e1x, b0);
    b1 = fmaf(w1[2*p + 1], e1y, b1);
  }

  v4f v; v.x = a0; v.y = a1; v.z = b0; v.w = b1;
  __builtin_nontemporal_store(v, (v4f*)ws + ((size_t)lvl * npts + pbase) / 2 + tid);
}

__global__ __launch_bounds__(TPB, 4) void transpose_out(
    const float* __restrict__ ws, float* __restrict__ out, int npts)
{
  __shared__ float lds[TPB * 33];
  const int tid = threadIdx.x;
  const size_t pbase = (size_t)blockIdx.x * TPB;
#pragma unroll
  for (int L = 0; L < NLEV; ++L) {
    const v2f w = __builtin_nontemporal_load((const v2f*)ws + (size_t)L * npts + pbase + tid);
    lds[tid * 33 + 2 * L]     = w.x;
    lds[tid * 33 + 2 * L + 1] = w.y;
  }
  __syncthreads();
  v4f* out4 = (v4f*)out + (size_t)blockIdx.x * (TPB * 32 / 4);
#pragma unroll
  for (int k = 0; k < 8; ++k) {
    const int q  = tid + k * TPB;
    const int p  = q >> 3;
    const int c4 = (q & 7) * 4;
    v4f v;
    v.x = lds[p * 33 + c4 + 0];
    v.y = lds[p * 33 + c4 + 1];
    v.z = lds[p * 33 + c4 + 2];
    v.w = lds[p * 33 + c4 + 3];
    __builtin_nontemporal_store(v, out4 + q);
  }
}

// ---------------------------------------------------------------------------
// Fallback monolithic kernel (proven correct) if ws is too small or the grid
// geometry assumptions don't hold.
// ---------------------------------------------------------------------------
__global__ __launch_bounds__(TPB) void hashenc_kernel(
    const float* __restrict__ pos, const float* __restrict__ table,
    float* __restrict__ out, ScaleParams spar)
{
  __shared__ float lds[TPB * 33];
  const int tid = threadIdx.x;
  const size_t pbase = (size_t)blockIdx.x * TPB;
  {
    const float* src = pos + pbase * 3;
    lds[tid]        = src[tid];
    lds[tid + 256]  = src[tid + 256];
    lds[tid + 512]  = src[tid + 512];
  }
  __syncthreads();
  const float px = lds[tid*3 + 0];
  const float py = lds[tid*3 + 1];
  const float pz = lds[tid*3 + 2];
  __syncthreads();

  const float2* __restrict__ tab2 = (const float2*)table;
  float acc[2 * NLEV];

#pragma unroll
  for (int L = 0; L < NLEV; ++L) {
    const float scale = spar.s[L];
    const float x = px * scale + 0.5f;
    const float y = py * scale + 0.5f;
    const float z = pz * scale + 0.5f;
    const float xf = floorf(x), yf = floorf(y), zf = floorf(z);
    const float tx = x - xf, ty = y - yf, tz = z - zf;
    const unsigned xi = (unsigned)xf, yi = (unsigned)yf, zi = (unsigned)zf;

    unsigned hx[2], hy[2], hz[2];
    if (kDense[L]) {
      const unsigned r = kRes[L];
      hx[0] = xi;          hx[1] = xi + 1u;
      hy[0] = yi * r;      hy[1] = (yi + 1u) * r;
      hz[0] = zi * r * r;  hz[1] = (zi + 1u) * r * r;
    } else {
      hx[0] = xi;                 hx[1] = xi + 1u;
      hy[0] = yi * 2654435761u;   hy[1] = (yi + 1u) * 2654435761u;
      hz[0] = zi * 805459861u;    hz[1] = (zi + 1u) * 805459861u;
    }
    const float wx[2] = {1.0f - tx, tx};
    const float wy[2] = {1.0f - ty, ty};
    const float wz[2] = {1.0f - tz, tz};

    float a0 = 0.0f, a1 = 0.0f;
#pragma unroll
    for (int c = 0; c < 8; ++c) {
      unsigned idx;
      if (kDense[L]) {
        unsigned h = hx[c & 1] + hy[(c >> 1) & 1] + hz[(c >> 2) & 1];
        idx = (h >= kMsz[L]) ? (h - kMsz[L]) : h;
      } else {
        idx = (hx[c & 1] ^ hy[(c >> 1) & 1] ^ hz[(c >> 2) & 1]) & (kMsz[L] - 1u);
      }
      const float2 f = tab2[kOff[L] + idx];
      const float w = wx[c & 1] * wy[(c >> 1) & 1] * wz[(c >> 2) & 1];
      a0 = fmaf(w, f.x, a0);
      a1 = fmaf(w, f.y, a1);
    }
    acc[2 * L]     = a0;
    acc[2 * L + 1] = a1;
  }

#pragma unroll
  for (int c = 0; c < 32; ++c) lds[tid * 33 + c] = acc[c];
  __syncthreads();

  v4f* out4 = (v4f*)out + (size_t)blockIdx.x * (TPB * 32 / 4);
#pragma unroll
  for (int k = 0; k < 8; ++k) {
    const int q  = tid + k * TPB;
    const int p  = q >> 3;
    const int c4 = (q & 7) * 4;
    v4f v;
    v.x = lds[p * 33 + c4 + 0];
    v.y = lds[p * 33 + c4 + 1];
    v.z = lds[p * 33 + c4 + 2];
    v.w = lds[p * 33 + c4 + 3];
    __builtin_nontemporal_store(v, out4 + q);
  }
}

extern "C" void kernel_launch(void* const* d_in, const int* in_sizes, int n_in,
                              void* d_out, int out_size, void* d_ws, size_t ws_size,
                              hipStream_t stream) {
  const float* pos   = (const float*)d_in[0];
  const float* table = (const float*)d_in[1];
  float* out = (float*)d_out;

  ScaleParams sp;
  for (int i = 0; i < NLEV; ++i)
    sp.s[i] = (float)(16.0 * exp((double)i * log(1.3195079565048218)) - 1.0);

  const int npts = in_sizes[0] / 3;   // 2097152
  const size_t need = (size_t)npts * 32 * sizeof(float);

  const int npair = npts / (TPB * 2);            // blocks per level at 2 pts/thread
  int sh = 0; while ((1 << sh) < npair) ++sh;
  const bool ok = (npts % (TPB * 2) == 0) && ((1 << sh) == npair);

  if (ws_size >= need && ok) {
    float* wsf = (float*)d_ws;
    dense_levels2<<<npair, TPB, 0, stream>>>(pos, table, wsf, sp, npts);
    hash_fused<<<npair * 10, TPB, 0, stream>>>(pos, table, wsf, sp, sh, npts);
    transpose_out<<<npts / TPB, TPB, 0, stream>>>(wsf, out, npts);
  } else {
    hashenc_kernel<<<npts / TPB, TPB, 0, stream>>>(pos, table, out, sp);
  }
}

// Round 7
// 1007.275 us; speedup vs baseline: 1.2157x; 1.2157x over previous
//
#include <hip/hip_runtime.h>
#include <cmath>

#define NLEV 16
#define TPB 256

typedef float v4f __attribute__((ext_vector_type(4)));
typedef float v2f __attribute__((ext_vector_type(2)));

// Level metadata replicated from the reference's _level_meta() (float64 host
// math; boundary levels 5/10/15 land 1e-5 ABOVE the integer -> res=65/257/1025).
static constexpr unsigned kRes[NLEV] = {16u,22u,28u,37u,49u,65u,85u,112u,148u,195u,257u,338u,446u,589u,777u,1025u};
static constexpr unsigned kMsz[NLEV] = {4096u,10648u,21952u,50656u,117656u,274632u,
  524288u,524288u,524288u,524288u,524288u,524288u,524288u,524288u,524288u,524288u};
static constexpr unsigned kOff[NLEV] = {0u,4096u,14744u,36696u,87352u,205008u,479640u,1003928u,
  1528216u,2052504u,2576792u,3101080u,3625368u,4149656u,4673944u,5198232u};
static constexpr int kDense[NLEV] = {1,1,1,1,1,1,0,0,0,0,0,0,0,0,0,0};

struct ScaleParams { float s[NLEV]; };

// 16-B load that is only guaranteed 8-B aligned (dense corner-pair load).
__device__ __forceinline__ v4f load4_a8(const float* p) {
  const float* q = (const float*)__builtin_assume_aligned((const void*)p, 8);
  v4f v;
  __builtin_memcpy(&v, q, 16);
  return v;
}

// Stage 512 points (2 per thread) of positions through LDS.
// stride 6 floats: gcd(6,32)=2 -> 2-way LDS aliasing, free on CDNA4.
__device__ __forceinline__ void load_pos2(const float* __restrict__ pos, float* sp,
                                          int tid, size_t pbase,
                                          float& px0, float& py0, float& pz0,
                                          float& px1, float& py1, float& pz1) {
  const float* src = pos + pbase * 3;
#pragma unroll
  for (int k = 0; k < 6; ++k)
    sp[tid + k * TPB] = __builtin_nontemporal_load(src + tid + k * TPB);
  __syncthreads();
  px0 = sp[tid * 6 + 0]; py0 = sp[tid * 6 + 1]; pz0 = sp[tid * 6 + 2];
  px1 = sp[tid * 6 + 3]; py1 = sp[tid * 6 + 4]; pz1 = sp[tid * 6 + 5];
}

// ---------------------------------------------------------------------------
// DENSE per-point body (round-1/round-5 form, byte-identical results):
// paired-corner 16B gathers (x and x+1 corners adjacent in the table),
// branchless wrap patch via hoisted scalar load of entry 0.
// NOTE (R6 lesson): 16B loads cost 2 transaction-units; this still wins for
// dense because the pair is ALWAYS adjacent (4x16B = 8 units, same as 8x8B,
// but half the addresses/instructions) and small tables hit L1.
// ---------------------------------------------------------------------------

__device__ __forceinline__ v2f dense_point(const float2* __restrict__ tab2,
                                           float px, float py, float pz,
                                           float scale, unsigned r, unsigned msz,
                                           unsigned off) {
  const float x = px * scale + 0.5f;
  const float y = py * scale + 0.5f;
  const float z = pz * scale + 0.5f;
  const float xf = floorf(x), yf = floorf(y), zf = floorf(z);
  const float tx = x - xf, ty = y - yf, tz = z - zf;
  const unsigned xi = (unsigned)xf, yi = (unsigned)yf, zi = (unsigned)zf;

  const unsigned hy[2] = {yi * r, (yi + 1u) * r};
  const unsigned hz[2] = {zi * r * r, (zi + 1u) * r * r};
  const float wx0 = 1.0f - tx, wx1 = tx;
  const float wy[2] = {1.0f - ty, ty};
  const float wz[2] = {1.0f - tz, tz};

  // wrap-patch value: corner x+1 of cell with idx==msz-1 lives at entry 0.
  const float2 g = tab2[off];

  float a0 = 0.0f, a1 = 0.0f;
#pragma unroll
  for (int c = 0; c < 4; ++c) {
    const unsigned h = xi + hy[c & 1] + hz[c >> 1];
    const unsigned idx = (h >= msz) ? (h - msz) : h;
    v4f f = load4_a8((const float*)(tab2 + (off + idx)));
    const bool wrap = (idx == msz - 1u);
    f.z = wrap ? g.x : f.z;
    f.w = wrap ? g.y : f.w;
    const float wyv = wy[c & 1], wzv = wz[c >> 1];
    const float w0 = (wx0 * wyv) * wzv;
    const float w1 = (wx1 * wyv) * wzv;
    a0 = fmaf(w0, f.x, a0);
    a1 = fmaf(w0, f.y, a1);
    a0 = fmaf(w1, f.z, a0);
    a1 = fmaf(w1, f.w, a1);
  }
  v2f rr; rr.x = a0; rr.y = a1;
  return rr;
}

// ---------------------------------------------------------------------------
// MERGED dense+hash dispatch (round-7 experiment).
// dense (200us) and hash (490us) are independent but ran serially = 690us of
// gather-wall time. Dense's gathers are largely L1-hits (levels 0-3 tables
// <=400KB) and only its miss fraction contends with hash's miss-path wall
// (~0.55 x 8B-units/cyc/CU, established R2-R6). One dispatch lets dense's
// L1-hit work co-issue under hash's miss latency. Dense blocks first
// (heaviest per block), then level-major hash blocks (L2 residency window).
// Per-point code of both paths is byte-identical to the verified R5 kernel.
// ---------------------------------------------------------------------------

__global__ __launch_bounds__(TPB, 4) void encode_all(
    const float* __restrict__ pos, const float* __restrict__ table,
    float* __restrict__ ws, ScaleParams spar, int lvlShift, int npts)
{
  __shared__ float sp[TPB * 6];
  const int tid = threadIdx.x;
  const unsigned npair = (unsigned)(npts / (TPB * 2));

  if (blockIdx.x < npair) {
    // ---------------- dense path: 6 levels for this point-block ------------
    const size_t pbase = (size_t)blockIdx.x * (TPB * 2);
    float px0, py0, pz0, px1, py1, pz1;
    load_pos2(pos, sp, tid, pbase, px0, py0, pz0, px1, py1, pz1);

    const float2* __restrict__ tab2 = (const float2*)table;
#pragma unroll
    for (int L = 0; L < 6; ++L) {
      const v2f r0 = dense_point(tab2, px0, py0, pz0, spar.s[L], kRes[L], kMsz[L], kOff[L]);
      const v2f r1 = dense_point(tab2, px1, py1, pz1, spar.s[L], kRes[L], kMsz[L], kOff[L]);
      v4f v; v.x = r0.x; v.y = r0.y; v.z = r1.x; v.w = r1.y;
      __builtin_nontemporal_store(v, (v4f*)ws + ((size_t)L * npts + pbase) / 2 + tid);
    }
    return;
  }

  // ------------------ hash path: one level, one point-block ----------------
  const unsigned hb = blockIdx.x - npair;
  const int lvl = 6 + (int)(hb >> lvlShift);
  const unsigned pb = hb & ((1u << lvlShift) - 1u);

  // uniform scalar select of this block's scale (avoids dynamic kernarg index)
  float scale = 0.0f;
#pragma unroll
  for (int l = 6; l < NLEV; ++l) if (l == lvl) scale = spar.s[l];
  const unsigned off = kOff[6] + (unsigned)(lvl - 6) * 524288u;

  const size_t pbase = (size_t)pb * (TPB * 2);
  float px0, py0, pz0, px1, py1, pz1;
  load_pos2(pos, sp, tid, pbase, px0, py0, pz0, px1, py1, pz1);

  unsigned i0[8], i1[8];
  float    w0[8], w1[8];
  {
    const float x = px0 * scale + 0.5f;
    const float y = py0 * scale + 0.5f;
    const float z = pz0 * scale + 0.5f;
    const float xf = floorf(x), yf = floorf(y), zf = floorf(z);
    const float tx = x - xf, ty = y - yf, tz = z - zf;
    const unsigned xi = (unsigned)xf, yi = (unsigned)yf, zi = (unsigned)zf;
    const unsigned hx[2] = {xi, xi + 1u};
    const unsigned hy[2] = {yi * 2654435761u, (yi + 1u) * 2654435761u};
    const unsigned hz[2] = {zi * 805459861u,  (zi + 1u) * 805459861u};
    const float wx[2] = {1.0f - tx, tx};
    const float wy[2] = {1.0f - ty, ty};
    const float wz[2] = {1.0f - tz, tz};
#pragma unroll
    for (int c = 0; c < 8; ++c) {
      i0[c] = (hx[c & 1] ^ hy[(c >> 1) & 1] ^ hz[(c >> 2) & 1]) & 524287u;
      w0[c] = wx[c & 1] * wy[(c >> 1) & 1] * wz[(c >> 2) & 1];
    }
  }
  {
    const float x = px1 * scale + 0.5f;
    const float y = py1 * scale + 0.5f;
    const float z = pz1 * scale + 0.5f;
    const float xf = floorf(x), yf = floorf(y), zf = floorf(z);
    const float tx = x - xf, ty = y - yf, tz = z - zf;
    const unsigned xi = (unsigned)xf, yi = (unsigned)yf, zi = (unsigned)zf;
    const unsigned hx[2] = {xi, xi + 1u};
    const unsigned hy[2] = {yi * 2654435761u, (yi + 1u) * 2654435761u};
    const unsigned hz[2] = {zi * 805459861u,  (zi + 1u) * 805459861u};
    const float wx[2] = {1.0f - tx, tx};
    const float wy[2] = {1.0f - ty, ty};
    const float wz[2] = {1.0f - tz, tz};
#pragma unroll
    for (int c = 0; c < 8; ++c) {
      i1[c] = (hx[c & 1] ^ hy[(c >> 1) & 1] ^ hz[(c >> 2) & 1]) & 524287u;
      w1[c] = wx[c & 1] * wy[(c >> 1) & 1] * wz[(c >> 2) & 1];
    }
  }

  const v2f* __restrict__ t2 = (const v2f*)table + off;
  v2f f0[8], f1[8];
#pragma unroll
  for (int c = 0; c < 8; ++c) f0[c] = t2[i0[c]];
#pragma unroll
  for (int c = 0; c < 8; ++c) f1[c] = t2[i1[c]];
  __builtin_amdgcn_sched_barrier(0);     // keep the gather group issued before use

  float a0 = 0.0f, a1 = 0.0f, b0 = 0.0f, b1 = 0.0f;
#pragma unroll
  for (int c = 0; c < 8; ++c) { a0 = fmaf(w0[c], f0[c].x, a0); a1 = fmaf(w0[c], f0[c].y, a1); }
#pragma unroll
  for (int c = 0; c < 8; ++c) { b0 = fmaf(w1[c], f1[c].x, b0); b1 = fmaf(w1[c], f1[c].y, b1); }

  v4f v; v.x = a0; v.y = a1; v.z = b0; v.w = b1;
  __builtin_nontemporal_store(v, (v4f*)ws + ((size_t)lvl * npts + pbase) / 2 + tid);
}

__global__ __launch_bounds__(TPB, 4) void transpose_out(
    const float* __restrict__ ws, float* __restrict__ out, int npts)
{
  __shared__ float lds[TPB * 33];
  const int tid = threadIdx.x;
  const size_t pbase = (size_t)blockIdx.x * TPB;
#pragma unroll
  for (int L = 0; L < NLEV; ++L) {
    const v2f w = __builtin_nontemporal_load((const v2f*)ws + (size_t)L * npts + pbase + tid);
    lds[tid * 33 + 2 * L]     = w.x;
    lds[tid * 33 + 2 * L + 1] = w.y;
  }
  __syncthreads();
  v4f* out4 = (v4f*)out + (size_t)blockIdx.x * (TPB * 32 / 4);
#pragma unroll
  for (int k = 0; k < 8; ++k) {
    const int q  = tid + k * TPB;
    const int p  = q >> 3;
    const int c4 = (q & 7) * 4;
    v4f v;
    v.x = lds[p * 33 + c4 + 0];
    v.y = lds[p * 33 + c4 + 1];
    v.z = lds[p * 33 + c4 + 2];
    v.w = lds[p * 33 + c4 + 3];
    __builtin_nontemporal_store(v, out4 + q);
  }
}

// ---------------------------------------------------------------------------
// Fallback monolithic kernel (proven correct) if ws is too small or the grid
// geometry assumptions don't hold.
// ---------------------------------------------------------------------------
__global__ __launch_bounds__(TPB) void hashenc_kernel(
    const float* __restrict__ pos, const float* __restrict__ table,
    float* __restrict__ out, ScaleParams spar)
{
  __shared__ float lds[TPB * 33];
  const int tid = threadIdx.x;
  const size_t pbase = (size_t)blockIdx.x * TPB;
  {
    const float* src = pos + pbase * 3;
    lds[tid]        = src[tid];
    lds[tid + 256]  = src[tid + 256];
    lds[tid + 512]  = src[tid + 512];
  }
  __syncthreads();
  const float px = lds[tid*3 + 0];
  const float py = lds[tid*3 + 1];
  const float pz = lds[tid*3 + 2];
  __syncthreads();

  const float2* __restrict__ tab2 = (const float2*)table;
  float acc[2 * NLEV];

#pragma unroll
  for (int L = 0; L < NLEV; ++L) {
    const float scale = spar.s[L];
    const float x = px * scale + 0.5f;
    const float y = py * scale + 0.5f;
    const float z = pz * scale + 0.5f;
    const float xf = floorf(x), yf = floorf(y), zf = floorf(z);
    const float tx = x - xf, ty = y - yf, tz = z - zf;
    const unsigned xi = (unsigned)xf, yi = (unsigned)yf, zi = (unsigned)zf;

    unsigned hx[2], hy[2], hz[2];
    if (kDense[L]) {
      const unsigned r = kRes[L];
      hx[0] = xi;          hx[1] = xi + 1u;
      hy[0] = yi * r;      hy[1] = (yi + 1u) * r;
      hz[0] = zi * r * r;  hz[1] = (zi + 1u) * r * r;
    } else {
      hx[0] = xi;                 hx[1] = xi + 1u;
      hy[0] = yi * 2654435761u;   hy[1] = (yi + 1u) * 2654435761u;
      hz[0] = zi * 805459861u;    hz[1] = (zi + 1u) * 805459861u;
    }
    const float wx[2] = {1.0f - tx, tx};
    const float wy[2] = {1.0f - ty, ty};
    const float wz[2] = {1.0f - tz, tz};

    float a0 = 0.0f, a1 = 0.0f;
#pragma unroll
    for (int c = 0; c < 8; ++c) {
      unsigned idx;
      if (kDense[L]) {
        unsigned h = hx[c & 1] + hy[(c >> 1) & 1] + hz[(c >> 2) & 1];
        idx = (h >= kMsz[L]) ? (h - kMsz[L]) : h;
      } else {
        idx = (hx[c & 1] ^ hy[(c >> 1) & 1] ^ hz[(c >> 2) & 1]) & (kMsz[L] - 1u);
      }
      const float2 f = tab2[kOff[L] + idx];
      const float w = wx[c & 1] * wy[(c >> 1) & 1] * wz[(c >> 2) & 1];
      a0 = fmaf(w, f.x, a0);
      a1 = fmaf(w, f.y, a1);
    }
    acc[2 * L]     = a0;
    acc[2 * L + 1] = a1;
  }

#pragma unroll
  for (int c = 0; c < 32; ++c) lds[tid * 33 + c] = acc[c];
  __syncthreads();

  v4f* out4 = (v4f*)out + (size_t)blockIdx.x * (TPB * 32 / 4);
#pragma unroll
  for (int k = 0; k < 8; ++k) {
    const int q  = tid + k * TPB;
    const int p  = q >> 3;
    const int c4 = (q & 7) * 4;
    v4f v;
    v.x = lds[p * 33 + c4 + 0];
    v.y = lds[p * 33 + c4 + 1];
    v.z = lds[p * 33 + c4 + 2];
    v.w = lds[p * 33 + c4 + 3];
    __builtin_nontemporal_store(v, out4 + q);
  }
}

extern "C" void kernel_launch(void* const* d_in, const int* in_sizes, int n_in,
                              void* d_out, int out_size, void* d_ws, size_t ws_size,
                              hipStream_t stream) {
  const float* pos   = (const float*)d_in[0];
  const float* table = (const float*)d_in[1];
  float* out = (float*)d_out;

  ScaleParams sp;
  for (int i = 0; i < NLEV; ++i)
    sp.s[i] = (float)(16.0 * exp((double)i * log(1.3195079565048218)) - 1.0);

  const int npts = in_sizes[0] / 3;   // 2097152
  const size_t need = (size_t)npts * 32 * sizeof(float);

  const int npair = npts / (TPB * 2);            // blocks per level at 2 pts/thread
  int sh = 0; while ((1 << sh) < npair) ++sh;
  const bool ok = (npts % (TPB * 2) == 0) && ((1 << sh) == npair);

  if (ws_size >= need && ok) {
    float* wsf = (float*)d_ws;
    // one dispatch: npair dense blocks (levels 0-5) + npair*10 hash blocks
    encode_all<<<npair * 11, TPB, 0, stream>>>(pos, table, wsf, sp, sh, npts);
    transpose_out<<<npts / TPB, TPB, 0, stream>>>(wsf, out, npts);
  } else {
    hashenc_kernel<<<npts / TPB, TPB, 0, stream>>>(pos, table, out, sp);
  }
}